// Round 14
// baseline (643.038 us; speedup 1.0000x reference)
//
#include <hip/hip_runtime.h>
#include <stdint.h>

#define THREADS 256
#define SPB 8                  // samples per block -> 32 A-rows
#define CHUNK_WORDS 4096       // one K=16 W chunk: hi plane 2048 + lo plane 2048 words
#define NCHUNK_TOT 64          // 4 layers x 16 chunks, linearized
#define ALO 4096               // sA lo-plane word offset (hi plane = [0,4096))

typedef __bf16 bf16x8 __attribute__((ext_vector_type(8)));
typedef float f32x16 __attribute__((ext_vector_type(16)));

union Frag { uint32_t u[4]; bf16x8 v; };

__device__ __forceinline__ uint32_t f2bf(float f) {    // RNE bf16 bits
    uint32_t u = __float_as_uint(f);
    return (u + 0x7fffu + ((u >> 16) & 1u)) >> 16;
}
__device__ __forceinline__ uint32_t pack_hilo(float f) { // bf16hi | bf16lo<<16
    uint32_t hb = f2bf(f);
    float hf = __uint_as_float(hb << 16);
    uint32_t lb = f2bf(f - hf);
    return hb | (lb << 16);
}
__device__ __forceinline__ float wsum(float v) {
    #pragma unroll
    for (int off = 32; off > 0; off >>= 1) v += __shfl_xor(v, off, 64);
    return v;
}
__device__ __forceinline__ float wmax(float v) {
    #pragma unroll
    for (int off = 32; off > 0; off >>= 1) v = fmaxf(v, __shfl_xor(v, off, 64));
    return v;
}

// ---- pre-kernel: pack W into planar hi/lo bf16 k-pair chunk images ----
// word idx = l*65536 + kt*4096 + plane*2048 + s8*1024 + n*4 + w
// holds bf16(k0)|bf16(k0+1)<<16 with k0 = kt*16 + s8*8 + 2w  (plane0=hi, plane1=lo)
__global__ __launch_bounds__(256) void pack_w(const float* __restrict__ w_hid,
                                              const float* __restrict__ w_out,
                                              uint32_t* __restrict__ Wp) {
    int idx = blockIdx.x * 256 + threadIdx.x;      // 0..262143
    int l     = idx >> 16;
    int r     = idx & 65535;
    int kt    = r >> 12;
    int r2    = r & 4095;
    int plane = r2 >> 11;
    int r3    = r2 & 2047;
    int s8    = r3 >> 10;
    int n     = (r3 >> 2) & 255;
    int w     = r3 & 3;
    int k0    = kt * 16 + s8 * 8 + 2 * w;
    const float* Wsrc = (l < 3) ? (w_hid + l * 65536) : w_out;
    float a = Wsrc[k0 * 256 + n];
    float b = Wsrc[(k0 + 1) * 256 + n];
    uint32_t ha = f2bf(a), hb = f2bf(b);
    uint32_t word;
    if (plane == 0) {
        word = ha | (hb << 16);
    } else {
        uint32_t la = f2bf(a - __uint_as_float(ha << 16));
        uint32_t lb = f2bf(b - __uint_as_float(hb << 16));
        word = la | (lb << 16);
    }
    Wp[idx] = word;
}

// sA planar layout (32 rows): plane + (kq<<7) + ((m ^ (kq&7))<<2) + (kp&3)
// kp = k>>1 (k-pair), kq = kp>>2 (16B line of 4 pairs = 8 k's), m = row 0..31.
// hi plane words [0,4096), lo plane [4096,8192). 32 KB total -> 4 blocks/CU
// (= 4 waves/SIMD) with VGPR <= 128.  256-thread blocks are the only shape
// where the allocator tracks demand (R13: 108 VGPR clean); (256,4) caps at 128.
__global__ __launch_bounds__(THREADS, 4) void divfree_mfma(
    const float* __restrict__ x,
    const uint32_t* __restrict__ Wp,
    const float* __restrict__ w_in,
    const float* __restrict__ b_in,
    const float* __restrict__ b_hid,
    const float* __restrict__ b_out,
    float* __restrict__ out)
{
    __shared__ uint32_t lds[8192];                 // 32 KB
    const int tid  = threadIdx.x;
    const int wave = tid >> 6, lane = tid & 63;
    const int l5 = lane >> 5, ln = lane & 31;
    const int s0 = blockIdx.x * SPB;
    // wave covers 64 cols: ct strips n = wave*64 + ct*32 + ln
    const int n4v0 = (wave * 64 + ln) * 4;
    const int n4v1 = n4v0 + 128;

    // 2-deep B queue, no copies: MFMAs consume q[slot] directly, refill after.
    uint4 qh[2][2], ql[2][2];                      // [slot][ct]
    #pragma unroll
    for (int sl = 0; sl < 2; ++sl) {
        const uint32_t* Bb = Wp + sl * CHUNK_WORDS + l5 * 1024;
        qh[sl][0] = *(const uint4*)(Bb + n4v0);
        ql[sl][0] = *(const uint4*)(Bb + 2048 + n4v0);
        qh[sl][1] = *(const uint4*)(Bb + n4v1);
        ql[sl][1] = *(const uint4*)(Bb + 2048 + n4v1);
    }

    { // ---- input layer: thread owns row m=tid&31, kq slabs i*8 + (tid>>5) ----
        const int m   = tid & 31;
        const int s   = m >> 2;
        const int row = m & 3;
        const float x0 = x[(s0 + s) * 3 + 0];
        const float x1 = x[(s0 + s) * 3 + 1];
        const float x2 = x[(s0 + s) * 3 + 2];
        #pragma unroll
        for (int i = 0; i < 4; ++i) {
            const int kq = i * 8 + (tid >> 5);     // 0..31
            const int k0 = kq * 8;
            uint32_t p[8];
            #pragma unroll
            for (int e4 = 0; e4 < 2; ++e4) {
                const int k = k0 + e4 * 4;
                float4 w0 = *(const float4*)&w_in[k];
                float4 w1 = *(const float4*)&w_in[256 + k];
                float4 w2 = *(const float4*)&w_in[512 + k];
                float4 bb = *(const float4*)&b_in[k];
                float W0[4] = {w0.x, w0.y, w0.z, w0.w};
                float W1[4] = {w1.x, w1.y, w1.z, w1.w};
                float W2[4] = {w2.x, w2.y, w2.z, w2.w};
                float BB[4] = {bb.x, bb.y, bb.z, bb.w};
                #pragma unroll
                for (int e = 0; e < 4; ++e) {
                    float pre = x0 * W0[e] + x1 * W1[e] + x2 * W2[e] + BB[e];
                    float sig = 1.f / (1.f + __expf(-pre));
                    float sp  = sig * (1.f + pre * (1.f - sig));
                    float wsel = (row == 1) ? W0[e] : (row == 2) ? W1[e] : W2[e];
                    float val  = (row == 0) ? pre * sig : sp * wsel;
                    p[e4 * 4 + e] = pack_hilo(val);
                }
            }
            uint32_t hw[4], lw[4];
            #pragma unroll
            for (int w = 0; w < 4; ++w) {
                hw[w] = __builtin_amdgcn_perm(p[2 * w + 1], p[2 * w], 0x05040100u);
                lw[w] = __builtin_amdgcn_perm(p[2 * w + 1], p[2 * w], 0x07060302u);
            }
            const int base = (kq << 7) + ((m ^ (kq & 7)) << 2);
            *(uint4*)&lds[base]       = *(uint4*)hw;
            *(uint4*)&lds[ALO + base] = *(uint4*)lw;
        }
    }
    __syncthreads();

    // A-frag LDS word bases: slot j = tt&3 (kq = 2*tt+l5 -> kq&7 period 4 in tt).
    // All A-reads = 4 VGPR bases + compile-time immediates ((tt>>2)*1024, +ALO).
    int abase[4];
    #pragma unroll
    for (int j = 0; j < 4; ++j) {
        const int kq = 2 * j + l5;
        abase[j] = (kq << 7) + ((ln ^ (kq & 7)) << 2);
    }

    #pragma unroll 1
    for (int l = 0; l < 4; ++l) {
        f32x16 acc[2];
        acc[0] = (f32x16)0.0f;
        acc[1] = (f32x16)0.0f;

        #pragma unroll
        for (int tt = 0; tt < 16; ++tt) {          // fully unrolled K-loop
            const int slot = tt & 1;

            // A frags: zero per-step address VALU (base reg + immediate)
            const int aw = abase[tt & 3] + (tt >> 2) * 1024;
            Frag ahi, alo;
            *(uint4*)&ahi.u[0] = *(const uint4*)&lds[aw];
            *(uint4*)&alo.u[0] = *(const uint4*)&lds[ALO + aw];

            #pragma unroll
            for (int ct = 0; ct < 2; ++ct) {
                Frag bhi, blo;
                *(uint4*)&bhi.u[0] = qh[slot][ct];
                *(uint4*)&blo.u[0] = ql[slot][ct];
                acc[ct] = __builtin_amdgcn_mfma_f32_32x32x16_bf16(ahi.v, bhi.v, acc[ct], 0, 0, 0);
                acc[ct] = __builtin_amdgcn_mfma_f32_32x32x16_bf16(alo.v, bhi.v, acc[ct], 0, 0, 0);
                acc[ct] = __builtin_amdgcn_mfma_f32_32x32x16_bf16(ahi.v, blo.v, acc[ct], 0, 0, 0);
            }

            // refill this slot with chunk lin+2 (after its last use this step)
            int lin = l * 16 + tt + 2;
            if (lin > NCHUNK_TOT - 1) lin = NCHUNK_TOT - 1;
            const uint32_t* Bb = Wp + lin * CHUNK_WORDS + l5 * 1024;
            qh[slot][0] = *(const uint4*)(Bb + n4v0);
            ql[slot][0] = *(const uint4*)(Bb + 2048 + n4v0);
            qh[slot][1] = *(const uint4*)(Bb + n4v1);
            ql[slot][1] = *(const uint4*)(Bb + 2048 + n4v1);
        }
        __syncthreads();                           // all waves done READING sA(l)

        if (l < 3) {
            // C layout: row = st + 8*rg + 4*l5, col = n
            #pragma unroll
            for (int ct = 0; ct < 2; ++ct) {
                const int n  = wave * 64 + ct * 32 + ln;
                const float bn = b_hid[l * 256 + n];
                const int kp = n >> 1;             // this lane-pair's k-pair
                const int kq = n >> 3;
                const int wbase = ((ln & 1) ? ALO : 0) + (kq << 7) + (kp & 3);
                #pragma unroll
                for (int rg = 0; rg < 4; ++rg) {
                    float pre = acc[ct][rg * 4 + 0] + bn;
                    float sig = 1.f / (1.f + __expf(-pre));
                    float sp  = sig * (1.f + pre * (1.f - sig));
                    float v[4];
                    v[0] = pre * sig;
                    v[1] = sp * acc[ct][rg * 4 + 1];
                    v[2] = sp * acc[ct][rg * 4 + 2];
                    v[3] = sp * acc[ct][rg * 4 + 3];
                    const int mb = 8 * rg + 4 * l5;
                    #pragma unroll
                    for (int st = 0; st < 4; ++st) {
                        uint32_t p = pack_hilo(v[st]);
                        uint32_t q = (uint32_t)__shfl_xor((int)p, 1, 64);
                        uint32_t word = (ln & 1)
                            ? __builtin_amdgcn_perm(p, q, 0x07060302u)
                            : __builtin_amdgcn_perm(q, p, 0x05040100u);
                        const int m = mb + st;
                        lds[wbase + ((m ^ (kq & 7)) << 2)] = word;
                    }
                }
            }
            __syncthreads();                       // sA(l+1) visible
        } else {
            // dump raw output-GEMM results to E[smp][state][n] fp32 (overlays sA)
            float* E = (float*)lds;
            #pragma unroll
            for (int ct = 0; ct < 2; ++ct) {
                const int n = wave * 64 + ct * 32 + ln;
                #pragma unroll
                for (int rg = 0; rg < 4; ++rg) {
                    const int smp = 2 * rg + l5;
                    #pragma unroll
                    for (int st = 0; st < 4; ++st)
                        E[(smp * 4 + st) * 256 + n] = acc[ct][rg * 4 + st];
                }
            }
            __syncthreads();
            // final phase: lane = mixture, wave w -> samples 2w..2w+1
            const float4* E4 = (const float4*)lds;
            float4 bo = *(const float4*)&b_out[lane * 4];
            #pragma unroll
            for (int g = 0; g < 2; ++g) {
                const int sl = wave * 2 + g;
                float4 o  = E4[(sl * 4 + 0) * 64 + lane];
                float4 t1 = E4[(sl * 4 + 1) * 64 + lane];
                float4 t2 = E4[(sl * 4 + 2) * 64 + lane];
                float4 t3 = E4[(sl * 4 + 3) * 64 + lane];
                float sm  = o.x + bo.x;
                float oa0 = o.y + bo.y, oa1 = o.z + bo.z, oa2 = o.w + bo.w;
                float ds0 = t1.x, ds1 = t2.x, ds2 = t3.x;
                float mx = wmax(sm);
                float e  = __expf(sm - mx);
                float Z  = wsum(e);
                float T0 = wsum(e * ds0) / Z;
                float T1 = wsum(e * ds1) / Z;
                float T2 = wsum(e * ds2) / Z;
                float g0 =  (ds1 - T1) * oa0 + t2.y + (ds2 - T2) * oa1 + t3.z;
                float g1 = -((ds0 - T0) * oa0 + t1.y) + (ds2 - T2) * oa2 + t3.w;
                float g2 = -((ds0 - T0) * oa1 + t1.z) - ((ds1 - T1) * oa2 + t2.w);
                float u0 = wsum(e * g0) / Z;
                float u1 = wsum(e * g1) / Z;
                float u2 = wsum(e * g2) / Z;
                if (lane == 0) {
                    const int sg = s0 + sl;
                    out[sg * 3 + 0] = u0;
                    out[sg * 3 + 1] = u1;
                    out[sg * 3 + 2] = u2;
                }
            }
        }
    }
}

extern "C" void kernel_launch(void* const* d_in, const int* in_sizes, int n_in,
                              void* d_out, int out_size, void* d_ws, size_t ws_size,
                              hipStream_t stream) {
    const float* x     = (const float*)d_in[0];
    const float* w_in  = (const float*)d_in[1];
    const float* b_in  = (const float*)d_in[2];
    const float* w_hid = (const float*)d_in[3];
    const float* b_hid = (const float*)d_in[4];
    const float* w_out = (const float*)d_in[5];
    const float* b_out = (const float*)d_in[6];
    float* out = (float*)d_out;
    uint32_t* Wp = (uint32_t*)d_ws;                 // 1 MB packed-weight image
    const int N = in_sizes[0] / 3;

    pack_w<<<1024, 256, 0, stream>>>(w_hid, w_out, Wp);
    divfree_mfma<<<N / SPB, THREADS, 0, stream>>>(x, Wp, w_in, b_in, b_hid, b_out, out);
}

// Round 15
// 541.072 us; speedup vs baseline: 1.1885x; 1.1885x over previous
//
#include <hip/hip_runtime.h>
#include <stdint.h>

#define THREADS 512
#define SPB 16                 // samples per block -> 64 A-rows
#define CHUNK_WORDS 4096       // one K=16 W chunk: hi plane 2048 + lo plane 2048 words
#define NCHUNK_TOT 64          // 4 layers x 16 chunks, linearized
#define ALO 8192               // sA lo-plane word offset (hi plane = [0,8192))

typedef __bf16 bf16x8 __attribute__((ext_vector_type(8)));
typedef float f32x16 __attribute__((ext_vector_type(16)));

union Frag { uint32_t u[4]; bf16x8 v; };

__device__ __forceinline__ uint32_t f2bf(float f) {    // RNE bf16 bits
    uint32_t u = __float_as_uint(f);
    return (u + 0x7fffu + ((u >> 16) & 1u)) >> 16;
}
__device__ __forceinline__ uint32_t pack_hilo(float f) { // bf16hi | bf16lo<<16
    uint32_t hb = f2bf(f);
    float hf = __uint_as_float(hb << 16);
    uint32_t lb = f2bf(f - hf);
    return hb | (lb << 16);
}
__device__ __forceinline__ float wsum(float v) {
    #pragma unroll
    for (int off = 32; off > 0; off >>= 1) v += __shfl_xor(v, off, 64);
    return v;
}
__device__ __forceinline__ float wmax(float v) {
    #pragma unroll
    for (int off = 32; off > 0; off >>= 1) v = fmaxf(v, __shfl_xor(v, off, 64));
    return v;
}

// ---- pre-kernel: pack W into planar hi/lo bf16 k-pair chunk images ----
// word idx = l*65536 + kt*4096 + plane*2048 + s8*1024 + n*4 + w
// holds bf16(k0)|bf16(k0+1)<<16 with k0 = kt*16 + s8*8 + 2w  (plane0=hi, plane1=lo)
__global__ __launch_bounds__(256) void pack_w(const float* __restrict__ w_hid,
                                              const float* __restrict__ w_out,
                                              uint32_t* __restrict__ Wp) {
    int idx = blockIdx.x * 256 + threadIdx.x;      // 0..262143
    int l     = idx >> 16;
    int r     = idx & 65535;
    int kt    = r >> 12;
    int r2    = r & 4095;
    int plane = r2 >> 11;
    int r3    = r2 & 2047;
    int s8    = r3 >> 10;
    int n     = (r3 >> 2) & 255;
    int w     = r3 & 3;
    int k0    = kt * 16 + s8 * 8 + 2 * w;
    const float* Wsrc = (l < 3) ? (w_hid + l * 65536) : w_out;
    float a = Wsrc[k0 * 256 + n];
    float b = Wsrc[(k0 + 1) * 256 + n];
    uint32_t ha = f2bf(a), hb = f2bf(b);
    uint32_t word;
    if (plane == 0) {
        word = ha | (hb << 16);
    } else {
        uint32_t la = f2bf(a - __uint_as_float(ha << 16));
        uint32_t lb = f2bf(b - __uint_as_float(hb << 16));
        word = la | (lb << 16);
    }
    Wp[idx] = word;
}

// sA planar layout (64 rows): plane + (kq<<8) + ((m ^ (kq&7))<<2) + (kp&3)
// kp = k>>1 (k-pair), kq = kp>>2 (16B line of 4 pairs = 8 k's), m = row 0..63.
// hi plane words [0,8192), lo plane [8192,16384). 64 KB total -> 2 blocks/CU.
// __launch_bounds__(512, 3): arg2 = min waves/EU per the CDNA guide -> VGPR
// budget 512/3 ~= 170 >= ~100 demand (goal: first clean 4-waves/SIMD config;
// {none,2,4} all collapsed to 64 VGPR + scratch spills on 512-thr blocks).
__global__ __launch_bounds__(THREADS, 3) void divfree_mfma(
    const float* __restrict__ x,
    const uint32_t* __restrict__ Wp,
    const float* __restrict__ w_in,
    const float* __restrict__ b_in,
    const float* __restrict__ b_hid,
    const float* __restrict__ b_out,
    float* __restrict__ out)
{
    __shared__ uint32_t lds[16384];                // 64 KB
    const int tid  = threadIdx.x;
    const int wave = tid >> 6, lane = tid & 63;
    const int l5 = lane >> 5, ln = lane & 31;
    const int s0 = blockIdx.x * SPB;
    const int n  = wave * 32 + ln;                 // this lane's output column
    const int n4v = n * 4;                         // B-frag word offset in a plane

    // 2-deep software-pipelined B prefetch, slots = tt&1 (linear chunk 0..63)
    uint4 qh[2], ql[2];
    {
        const uint32_t* Bb0 = Wp + l5 * 1024;
        const uint32_t* Bb1 = Wp + CHUNK_WORDS + l5 * 1024;
        qh[0] = *(const uint4*)(Bb0 + n4v);
        ql[0] = *(const uint4*)(Bb0 + 2048 + n4v);
        qh[1] = *(const uint4*)(Bb1 + n4v);
        ql[1] = *(const uint4*)(Bb1 + 2048 + n4v);
    }

    { // ---- input layer: thread owns row m=tid&63, kq slabs i*8 + (tid>>6) ----
        const int m   = tid & 63;
        const int s   = m >> 2;
        const int row = m & 3;
        const float x0 = x[(s0 + s) * 3 + 0];
        const float x1 = x[(s0 + s) * 3 + 1];
        const float x2 = x[(s0 + s) * 3 + 2];
        #pragma unroll
        for (int i = 0; i < 4; ++i) {
            const int kq = i * 8 + (tid >> 6);     // 0..31
            const int k0 = kq * 8;
            uint32_t p[8];
            #pragma unroll
            for (int e4 = 0; e4 < 2; ++e4) {
                const int k = k0 + e4 * 4;
                float4 w0 = *(const float4*)&w_in[k];
                float4 w1 = *(const float4*)&w_in[256 + k];
                float4 w2 = *(const float4*)&w_in[512 + k];
                float4 bb = *(const float4*)&b_in[k];
                float W0[4] = {w0.x, w0.y, w0.z, w0.w};
                float W1[4] = {w1.x, w1.y, w1.z, w1.w};
                float W2[4] = {w2.x, w2.y, w2.z, w2.w};
                float BB[4] = {bb.x, bb.y, bb.z, bb.w};
                #pragma unroll
                for (int e = 0; e < 4; ++e) {
                    float pre = x0 * W0[e] + x1 * W1[e] + x2 * W2[e] + BB[e];
                    float sig = 1.f / (1.f + __expf(-pre));
                    float sp  = sig * (1.f + pre * (1.f - sig));
                    float wsel = (row == 1) ? W0[e] : (row == 2) ? W1[e] : W2[e];
                    float val  = (row == 0) ? pre * sig : sp * wsel;
                    p[e4 * 4 + e] = pack_hilo(val);
                }
            }
            uint32_t hw[4], lw[4];
            #pragma unroll
            for (int w = 0; w < 4; ++w) {
                hw[w] = __builtin_amdgcn_perm(p[2 * w + 1], p[2 * w], 0x05040100u);
                lw[w] = __builtin_amdgcn_perm(p[2 * w + 1], p[2 * w], 0x07060302u);
            }
            const int base = (kq << 8) + ((m ^ (kq & 7)) << 2);
            *(uint4*)&lds[base]       = *(uint4*)hw;
            *(uint4*)&lds[ALO + base] = *(uint4*)lw;
        }
    }
    __syncthreads();

    // A-frag LDS word bases: slot j = tt&3 (kq = 2*tt+l5 -> kq&7 period 4 in tt).
    // All A-reads = 4 VGPR bases + compile-time immediates ((tt>>2)*2048, +ALO).
    int abase[4];
    #pragma unroll
    for (int j = 0; j < 4; ++j) {
        const int kq = 2 * j + l5;
        abase[j] = (kq << 8) + ((ln ^ (kq & 7)) << 2);
    }

    #pragma unroll 1
    for (int l = 0; l < 4; ++l) {
        f32x16 acc[2];
        acc[0] = (f32x16)0.0f;
        acc[1] = (f32x16)0.0f;

        #pragma unroll
        for (int tt = 0; tt < 16; ++tt) {          // fully unrolled K-loop
            const int slot = tt & 1;
            Frag bhi, blo;
            *(uint4*)&bhi.u[0] = qh[slot];
            *(uint4*)&blo.u[0] = ql[slot];
            // refill this slot with chunk lin+2 (uniform -> scalar pipe)
            int lin = l * 16 + tt + 2;
            if (lin > NCHUNK_TOT - 1) lin = NCHUNK_TOT - 1;
            const uint32_t* Bb = Wp + lin * CHUNK_WORDS + l5 * 1024;
            qh[slot] = *(const uint4*)(Bb + n4v);
            ql[slot] = *(const uint4*)(Bb + 2048 + n4v);

            // A frags: zero per-step address VALU (base reg + immediate)
            const int aw = abase[tt & 3] + (tt >> 2) * 2048;
            Frag ahi[2], alo[2];
            #pragma unroll
            for (int rt = 0; rt < 2; ++rt) {
                *(uint4*)&ahi[rt].u[0] = *(const uint4*)&lds[aw + rt * 128];
                *(uint4*)&alo[rt].u[0] = *(const uint4*)&lds[ALO + aw + rt * 128];
            }
            #pragma unroll
            for (int rt = 0; rt < 2; ++rt) {
                acc[rt] = __builtin_amdgcn_mfma_f32_32x32x16_bf16(ahi[rt].v, bhi.v, acc[rt], 0, 0, 0);
                acc[rt] = __builtin_amdgcn_mfma_f32_32x32x16_bf16(alo[rt].v, bhi.v, acc[rt], 0, 0, 0);
                acc[rt] = __builtin_amdgcn_mfma_f32_32x32x16_bf16(ahi[rt].v, blo.v, acc[rt], 0, 0, 0);
            }
        }
        __syncthreads();                           // all waves done READING sA(l)

        if (l < 3) {
            // C layout: row = st + 8*rg + 4*l5 (+rt*32), col = n
            const float bn = b_hid[l * 256 + n];
            const int kp = n >> 1;                 // this lane-pair's k-pair
            const int kq = n >> 3;
            const int wbase = ((ln & 1) ? ALO : 0) + (kq << 8) + (kp & 3);
            #pragma unroll
            for (int rt = 0; rt < 2; ++rt) {
                #pragma unroll
                for (int rg = 0; rg < 4; ++rg) {
                    float pre = acc[rt][rg * 4 + 0] + bn;
                    float sig = 1.f / (1.f + __expf(-pre));
                    float sp  = sig * (1.f + pre * (1.f - sig));
                    float v[4];
                    v[0] = pre * sig;
                    v[1] = sp * acc[rt][rg * 4 + 1];
                    v[2] = sp * acc[rt][rg * 4 + 2];
                    v[3] = sp * acc[rt][rg * 4 + 3];
                    const int mb = rt * 32 + 8 * rg + 4 * l5;
                    #pragma unroll
                    for (int st = 0; st < 4; ++st) {
                        uint32_t p = pack_hilo(v[st]);
                        uint32_t q = (uint32_t)__shfl_xor((int)p, 1, 64);
                        uint32_t word = (ln & 1)
                            ? __builtin_amdgcn_perm(p, q, 0x07060302u)
                            : __builtin_amdgcn_perm(q, p, 0x05040100u);
                        const int m = mb + st;
                        lds[wbase + ((m ^ (kq & 7)) << 2)] = word;
                    }
                }
            }
            __syncthreads();                       // sA(l+1) visible
        } else {
            // dump raw output-GEMM results to E[smp][state][n] fp32 (overlays sA)
            float* E = (float*)lds;
            #pragma unroll
            for (int rt = 0; rt < 2; ++rt) {
                #pragma unroll
                for (int rg = 0; rg < 4; ++rg) {
                    const int smp = rt * 8 + 2 * rg + l5;
                    #pragma unroll
                    for (int st = 0; st < 4; ++st)
                        E[(smp * 4 + st) * 256 + n] = acc[rt][rg * 4 + st];
                }
            }
            __syncthreads();
            // final phase: lane = mixture, wave w -> samples 2w..2w+1
            const float4* E4 = (const float4*)lds;
            float4 bo = *(const float4*)&b_out[lane * 4];
            #pragma unroll
            for (int g = 0; g < 2; ++g) {
                const int sl = wave * 2 + g;
                float4 o  = E4[(sl * 4 + 0) * 64 + lane];
                float4 t1 = E4[(sl * 4 + 1) * 64 + lane];
                float4 t2 = E4[(sl * 4 + 2) * 64 + lane];
                float4 t3 = E4[(sl * 4 + 3) * 64 + lane];
                float sm  = o.x + bo.x;
                float oa0 = o.y + bo.y, oa1 = o.z + bo.z, oa2 = o.w + bo.w;
                float ds0 = t1.x, ds1 = t2.x, ds2 = t3.x;
                float mx = wmax(sm);
                float e  = __expf(sm - mx);
                float Z  = wsum(e);
                float T0 = wsum(e * ds0) / Z;
                float T1 = wsum(e * ds1) / Z;
                float T2 = wsum(e * ds2) / Z;
                float g0 =  (ds1 - T1) * oa0 + t2.y + (ds2 - T2) * oa1 + t3.z;
                float g1 = -((ds0 - T0) * oa0 + t1.y) + (ds2 - T2) * oa2 + t3.w;
                float g2 = -((ds0 - T0) * oa1 + t1.z) - ((ds1 - T1) * oa2 + t2.w);
                float u0 = wsum(e * g0) / Z;
                float u1 = wsum(e * g1) / Z;
                float u2 = wsum(e * g2) / Z;
                if (lane == 0) {
                    const int sg = s0 + sl;
                    out[sg * 3 + 0] = u0;
                    out[sg * 3 + 1] = u1;
                    out[sg * 3 + 2] = u2;
                }
            }
        }
    }
}

extern "C" void kernel_launch(void* const* d_in, const int* in_sizes, int n_in,
                              void* d_out, int out_size, void* d_ws, size_t ws_size,
                              hipStream_t stream) {
    const float* x     = (const float*)d_in[0];
    const float* w_in  = (const float*)d_in[1];
    const float* b_in  = (const float*)d_in[2];
    const float* w_hid = (const float*)d_in[3];
    const float* b_hid = (const float*)d_in[4];
    const float* w_out = (const float*)d_in[5];
    const float* b_out = (const float*)d_in[6];
    float* out = (float*)d_out;
    uint32_t* Wp = (uint32_t*)d_ws;                 // 1 MB packed-weight image
    const int N = in_sizes[0] / 3;

    pack_w<<<1024, 256, 0, stream>>>(w_hid, w_out, Wp);
    divfree_mfma<<<N / SPB, THREADS, 0, stream>>>(x, Wp, w_in, b_in, b_hid, b_out, out);
}